// Round 10
// baseline (464.993 us; speedup 1.0000x reference)
//
#include <hip/hip_runtime.h>

#define D_IN  256
#define D_HID 512
#define NEG_SLOPE 0.2f
#define SCAN_CHUNK 2048

typedef __attribute__((ext_vector_type(8))) short short8;
typedef __attribute__((ext_vector_type(4))) float floatx4;

__device__ __forceinline__ unsigned short f2bf(float f) {
    unsigned int u = __float_as_uint(f);
    u += 0x7fffu + ((u >> 16) & 1u);   // round-to-nearest-even
    return (unsigned short)(u >> 16);
}
__device__ __forceinline__ float bf2f(unsigned short u) {
    return __uint_as_float(((unsigned int)u) << 16);
}

__device__ __forceinline__ int eidx(const void* ei, long pos, int is64) {
    return is64 ? (int)((const long long*)ei)[pos] : ((const int*)ei)[pos];
}

// ---- init: x->bf16, zero deg, dtype detect (block 0), weight transposes, outacc init ----
__global__ __launch_bounds__(256) void k_init(const float* __restrict__ x,
                                              unsigned short* __restrict__ xb,
                                              int* __restrict__ deg, int N,
                                              const unsigned int* __restrict__ ei,
                                              int npairs, int* flag,
                                              const float* __restrict__ W_gcn,
                                              unsigned short* __restrict__ Wgt,
                                              const float* __restrict__ W2,
                                              unsigned short* __restrict__ W2t,
                                              const float* __restrict__ b_out,
                                              float* __restrict__ outacc,
                                              long xthreads) {
    long t = (long)blockIdx.x * blockDim.x + threadIdx.x;
    if (t < xthreads) {
        long i = t * 4;
        float4 v = *(const float4*)(x + i);
        ushort4 o;
        o.x = f2bf(v.x); o.y = f2bf(v.y); o.z = f2bf(v.z); o.w = f2bf(v.w);
        *(ushort4*)(xb + i) = o;
        if (t < N) deg[t] = 0;
        if (blockIdx.x == 0) {
            __shared__ int nz;
            if (threadIdx.x == 0) nz = 0;
            __syncthreads();
            for (int p = threadIdx.x; p < npairs; p += blockDim.x)
                if (ei[2 * p + 1] != 0) nz = 1;
            __syncthreads();
            if (threadIdx.x == 0) *flag = nz ? 0 : 1;   // 1 => int64
        }
        return;
    }
    long u = t - xthreads;
    if (u < (long)D_IN * D_HID) {                 // Wgt [512,256]
        int tt = (int)u;
        int n = tt / D_IN, k = tt - n * D_IN;
        Wgt[tt] = f2bf(W_gcn[(long)k * D_HID + n]);
        return;
    }
    u -= (long)D_IN * D_HID;
    if (u < (long)D_HID * D_HID) {                // W2t [512,512]
        int tt = (int)u;
        int n = tt / D_HID, k = tt - n * D_HID;
        W2t[tt] = f2bf(W2[(long)k * D_HID + n]);
        return;
    }
    u -= (long)D_HID * D_HID;
    if (u < N) outacc[u] = b_out[0];
}

// ---- degree count (int only) ----
__global__ void k_deg_count(const void* __restrict__ ei, const int* __restrict__ flag,
                            int* __restrict__ deg, int E) {
    int e = blockIdx.x * blockDim.x + threadIdx.x;
    if (e < E) atomicAdd(&deg[eidx(ei, (long)E + e, *flag)], 1);
}

// ---- scan phase 1: per-chunk sums ----
__global__ __launch_bounds__(256) void k_scan1(const int* __restrict__ deg,
                                               int* __restrict__ bsum, int N) {
    int base = blockIdx.x * SCAN_CHUNK;
    int hi = min(base + SCAN_CHUNK, N);
    int s = 0;
    for (int i = base + threadIdx.x; i < hi; i += 256) s += deg[i];
#pragma unroll
    for (int off = 32; off > 0; off >>= 1) s += __shfl_down(s, off, 64);
    __shared__ int lds[4];
    if ((threadIdx.x & 63) == 0) lds[threadIdx.x >> 6] = s;
    __syncthreads();
    if (threadIdx.x == 0) bsum[blockIdx.x] = lds[0] + lds[1] + lds[2] + lds[3];
}

// ---- scan phases 2+3 merged: each block redundantly scans bsum, then local scan ----
__global__ __launch_bounds__(256) void k_scan23(const int* __restrict__ deg,
                                                const int* __restrict__ bsum, int NB,
                                                int* __restrict__ offs,
                                                int* __restrict__ cursor,
                                                float* __restrict__ dinv, int N) {
    __shared__ int lds[256];
    int t = threadIdx.x;
    int bbase = 0;
    for (int i = 0; i < NB; ++i) bbase += (i < blockIdx.x) ? bsum[i] : 0;
    if (blockIdx.x == NB - 1 && t == 0) offs[N] = bbase + bsum[NB - 1];
    int base = blockIdx.x * SCAN_CHUNK;
    int lo = base + t * 8;
    int v[8], s = 0;
#pragma unroll
    for (int j = 0; j < 8; ++j) {
        int i = lo + j;
        v[j] = (i < N) ? deg[i] : 0;
        s += v[j];
    }
    lds[t] = s;
    __syncthreads();
    for (int d = 1; d < 256; d <<= 1) {
        int add = (t >= d) ? lds[t - d] : 0;
        __syncthreads();
        lds[t] += add;
        __syncthreads();
    }
    int run = bbase + ((t > 0) ? lds[t - 1] : 0);
#pragma unroll
    for (int j = 0; j < 8; ++j) {
        int i = lo + j;
        if (i < N) {
            offs[i] = run; cursor[i] = run;
            dinv[i] = rsqrtf(1.0f + (float)v[j]);
            run += v[j];
        }
    }
}

// ---- fill CSR edge list (src per slot, dst-sorted) ----
__global__ void k_fill(const void* __restrict__ ei, const int* __restrict__ flag,
                       int* __restrict__ cursor, int* __restrict__ esrc, int E) {
    int e = blockIdx.x * blockDim.x + threadIdx.x;
    if (e >= E) return;
    int is64 = *flag;
    int s = eidx(ei, e, is64), d = eidx(ei, (long)E + e, is64);
    int pos = atomicAdd(&cursor[d], 1);
    esrc[pos] = s;
}

// ---- XCD-sliced gather: slice = blockIdx&7 pins a 32-col slice of xb (3.2 MB) per XCD ----
// wave = 1 node; 16 lanes x ushort2 = 32 cols; 4 edge-subgroups; 8 edges in flight
__global__ __launch_bounds__(256) void k_gather8(const unsigned short* __restrict__ xb,
                                                 const int* __restrict__ offs,
                                                 const int* __restrict__ esrc,
                                                 const float* __restrict__ dinv,
                                                 unsigned short* __restrict__ aggb, int N) {
    int b = blockIdx.x;
    int slice = b & 7;
    int node = (b >> 3) * 4 + (threadIdx.x >> 6);
    if (node >= N) return;
    int lane = threadIdx.x & 63;
    int grp  = lane >> 4;
    int colbase = slice * 32 + (lane & 15) * 2;
    float di = dinv[node];

    float a0 = 0.f, a1 = 0.f;
    if (grp == 0) {   // self-loop term, weight di (x di at the end)
        unsigned int u = *(const unsigned int*)(xb + (long)node * D_IN + colbase);
        a0 = di * bf2f((unsigned short)(u & 0xffff));
        a1 = di * bf2f((unsigned short)(u >> 16));
    }

    int beg = offs[node], end = offs[node + 1];
    int e = beg;
    for (; e + 8 <= end; e += 8) {          // two independent 4-edge chains
        int j0 = e + grp, j1 = e + 4 + grp;
        int s0 = esrc[j0], s1 = esrc[j1];
        float w0 = dinv[s0], w1 = dinv[s1];
        unsigned int u0 = *(const unsigned int*)(xb + (long)s0 * D_IN + colbase);
        unsigned int u1 = *(const unsigned int*)(xb + (long)s1 * D_IN + colbase);
        a0 += w0 * bf2f((unsigned short)(u0 & 0xffff)) + w1 * bf2f((unsigned short)(u1 & 0xffff));
        a1 += w0 * bf2f((unsigned short)(u0 >> 16))    + w1 * bf2f((unsigned short)(u1 >> 16));
    }
    for (; e < end; e += 4) {               // guarded tail
        int j = e + grp;
        int jj = (j < end) ? j : end - 1;
        int s = esrc[jj];
        float w = (j < end) ? dinv[s] : 0.f;
        unsigned int u = *(const unsigned int*)(xb + (long)s * D_IN + colbase);
        a0 += w * bf2f((unsigned short)(u & 0xffff));
        a1 += w * bf2f((unsigned short)(u >> 16));
    }

    a0 += __shfl_xor(a0, 16, 64); a0 += __shfl_xor(a0, 32, 64);
    a1 += __shfl_xor(a1, 16, 64); a1 += __shfl_xor(a1, 32, 64);
    if (grp == 0) {
        unsigned short o0 = f2bf(a0 * di), o1 = f2bf(a1 * di);
        *(unsigned int*)(aggb + (long)node * D_IN + colbase) = ((unsigned int)o1 << 16) | o0;
    }
}

// ============ swizzled-LDS 128x128 GEMM machinery (round-9, unchanged) ============
__device__ __forceinline__ void async_cp16(const unsigned short* gp, unsigned short* lp) {
    __builtin_amdgcn_global_load_lds((const __attribute__((address_space(1))) void*)gp,
                                     (__attribute__((address_space(3))) void*)lp, 16, 0, 0);
}

__device__ __forceinline__ void stage_sw(const unsigned short* src, int strideK,
                                         int rowMax, unsigned short* lds, int tid) {
#pragma unroll
    for (int rr = 0; rr < 2; ++rr) {
        int c = rr * 256 + tid;
        int p = c >> 3;
        int ci = (c & 7) ^ (p & 7);
        int row = 2 * p + (ci >> 2);
        if (row > rowMax) row = rowMax;
        async_cp16(src + (long)row * strideK + (ci & 3) * 8, lds + c * 8);
    }
}

__device__ __forceinline__ bool map_block(int b, int M, int& m0, int& n0) {
    int x = b & 7, slot = b >> 3;
    int mt = x + 8 * (slot >> 2);
    m0 = mt * 128; n0 = (slot & 3) * 128;
    return m0 < M;
}

// ---- GEMM1: C[M,512] = bf16(leaky(A[M,K] @ Bt[512,K]^T + bias)) ----
__global__ __launch_bounds__(256) void k_gemm_bf16(const unsigned short* __restrict__ A,
                                                   const unsigned short* __restrict__ Bt,
                                                   const float* __restrict__ bias,
                                                   unsigned short* __restrict__ C,
                                                   int M, int K) {
    __shared__ __align__(16) unsigned short As[128 * 32];
    __shared__ __align__(16) unsigned short Bs[128 * 32];
    const int tid  = threadIdx.x;
    const int lane = tid & 63, wave = tid >> 6;
    int m0, n0;
    if (!map_block(blockIdx.x, M, m0, n0)) return;
    const int r = lane & 15, q = lane >> 4;
    const int rh = r >> 1;
    const int sa = (((r & 1) << 2) | q) ^ rh;
    const int wm = (wave & 1) * 64, wn = (wave >> 1) * 64;

    floatx4 acc[4][4];
#pragma unroll
    for (int i = 0; i < 4; ++i)
#pragma unroll
        for (int j = 0; j < 4; ++j) acc[i][j] = (floatx4){0.f, 0.f, 0.f, 0.f};

    for (int k0 = 0; k0 < K; k0 += 32) {
        stage_sw(A + (long)m0 * K + k0, K, M - 1 - m0, As, tid);
        stage_sw(Bt + (long)n0 * K + k0, K, 127, Bs, tid);
        __syncthreads();

        short8 af[4], bf[4];
#pragma unroll
        for (int i = 0; i < 4; ++i)
            af[i] = *(const short8*)(As + (wm / 2 + i * 8 + rh) * 64 + sa * 8);
#pragma unroll
        for (int j = 0; j < 4; ++j)
            bf[j] = *(const short8*)(Bs + (wn / 2 + j * 8 + rh) * 64 + sa * 8);
#pragma unroll
        for (int i = 0; i < 4; ++i)
#pragma unroll
            for (int j = 0; j < 4; ++j)
                acc[i][j] = __builtin_amdgcn_mfma_f32_16x16x32_bf16(af[i], bf[j], acc[i][j], 0, 0, 0);
        __syncthreads();
    }

#pragma unroll
    for (int j = 0; j < 4; ++j) {
        int col = n0 + wn + j * 16 + r;
        float bv = bias[col];
#pragma unroll
        for (int i = 0; i < 4; ++i) {
#pragma unroll
            for (int t2 = 0; t2 < 4; ++t2) {
                int row = m0 + wm + i * 16 + q * 4 + t2;
                if (row < M) {
                    float v = acc[i][j][t2] + bv;
                    v = v > 0.f ? v : NEG_SLOPE * v;
                    C[(long)row * D_HID + col] = f2bf(v);
                }
            }
        }
    }
}

// ---- GEMM2 fused with head: outacc[row] += sum_col leaky(A@Bt^T + b2) * wout[col] ----
__global__ __launch_bounds__(256) void k_gemm2f(const unsigned short* __restrict__ A,
                                                const unsigned short* __restrict__ Bt,
                                                const float* __restrict__ bias,
                                                const float* __restrict__ wout,
                                                float* __restrict__ outacc,
                                                int M, int K) {
    __shared__ __align__(16) unsigned short As[128 * 32];
    __shared__ __align__(16) unsigned short Bs[128 * 32];
    const int tid  = threadIdx.x;
    const int lane = tid & 63, wave = tid >> 6;
    int m0, n0;
    if (!map_block(blockIdx.x, M, m0, n0)) return;
    const int r = lane & 15, q = lane >> 4;
    const int rh = r >> 1;
    const int sa = (((r & 1) << 2) | q) ^ rh;
    const int wm = (wave & 1) * 64, wn = (wave >> 1) * 64;

    floatx4 acc[4][4];
#pragma unroll
    for (int i = 0; i < 4; ++i)
#pragma unroll
        for (int j = 0; j < 4; ++j) acc[i][j] = (floatx4){0.f, 0.f, 0.f, 0.f};

    for (int k0 = 0; k0 < K; k0 += 32) {
        stage_sw(A + (long)m0 * K + k0, K, M - 1 - m0, As, tid);
        stage_sw(Bt + (long)n0 * K + k0, K, 127, Bs, tid);
        __syncthreads();

        short8 af[4], bf[4];
#pragma unroll
        for (int i = 0; i < 4; ++i)
            af[i] = *(const short8*)(As + (wm / 2 + i * 8 + rh) * 64 + sa * 8);
#pragma unroll
        for (int j = 0; j < 4; ++j)
            bf[j] = *(const short8*)(Bs + (wn / 2 + j * 8 + rh) * 64 + sa * 8);
#pragma unroll
        for (int i = 0; i < 4; ++i)
#pragma unroll
            for (int j = 0; j < 4; ++j)
                acc[i][j] = __builtin_amdgcn_mfma_f32_16x16x32_bf16(af[i], bf[j], acc[i][j], 0, 0, 0);
        __syncthreads();
    }

    float bv[4], wv[4];
#pragma unroll
    for (int j = 0; j < 4; ++j) {
        int col = n0 + wn + j * 16 + r;
        bv[j] = bias[col];
        wv[j] = wout[col];
    }
#pragma unroll
    for (int i = 0; i < 4; ++i) {
#pragma unroll
        for (int t2 = 0; t2 < 4; ++t2) {
            float p = 0.f;
#pragma unroll
            for (int j = 0; j < 4; ++j) {
                float v = acc[i][j][t2] + bv[j];
                v = v > 0.f ? v : NEG_SLOPE * v;
                p += v * wv[j];
            }
            p += __shfl_xor(p, 8, 64);
            p += __shfl_xor(p, 4, 64);
            p += __shfl_xor(p, 2, 64);
            p += __shfl_xor(p, 1, 64);
            if (r == 0) {
                int row = m0 + wm + i * 16 + q * 4 + t2;
                if (row < M) atomicAdd(&outacc[row], p);
            }
        }
    }
}

// ---- final: plain-store copy outacc (ws) -> d_out ----
__global__ void k_out(const float* __restrict__ outacc, float* __restrict__ out, int N) {
    int i = blockIdx.x * blockDim.x + threadIdx.x;
    if (i < N) out[i] = outacc[i];
}

extern "C" void kernel_launch(void* const* d_in, const int* in_sizes, int n_in,
                              void* d_out, int out_size, void* d_ws, size_t ws_size,
                              hipStream_t stream) {
    const float* x     = (const float*)d_in[0];
    const void*  ei    = d_in[1];
    const float* W_gcn = (const float*)d_in[2];
    const float* b_gcn = (const float*)d_in[3];
    const float* W2    = (const float*)d_in[4];
    const float* b2    = (const float*)d_in[5];
    const float* W_out = (const float*)d_in[6];
    const float* b_out = (const float*)d_in[7];
    float* out = (float*)d_out;

    const int N = in_sizes[0] / D_IN;
    const int E = in_sizes[1] / 2;
    const int NB = (N + SCAN_CHUNK - 1) / SCAN_CHUNK;

    char* w = (char*)d_ws;
    size_t off = 0;
    auto alloc = [&](size_t bytes) { char* p = w + off; off = (off + bytes + 255) & ~(size_t)255; return p; };
    int*            flag   = (int*)alloc(256);
    float*          dinv   = (float*)alloc((size_t)N * 4);
    int*            deg_i  = (int*)alloc((size_t)N * 4);
    int*            offs   = (int*)alloc((size_t)(N + 1) * 4);
    int*            cursor = (int*)alloc((size_t)N * 4);
    float*          outacc = (float*)alloc((size_t)N * 4);
    int*            bsum   = (int*)alloc((size_t)NB * 4);
    int*            esrc   = (int*)alloc((size_t)(E + 8) * 4);
    unsigned short* xb     = (unsigned short*)alloc((size_t)N * D_IN * 2);
    unsigned short* aggb   = (unsigned short*)alloc((size_t)N * D_IN * 2);
    unsigned short* h1     = (unsigned short*)alloc((size_t)N * D_HID * 2);
    unsigned short* Wgt    = (unsigned short*)alloc((size_t)D_IN * D_HID * 2);
    unsigned short* W2t    = (unsigned short*)alloc((size_t)D_HID * D_HID * 2);

    int npairs = E < 2048 ? E : 2048;
    long xthreads = ((long)N * D_IN) / 4;
    long prep_elems = (long)D_IN * D_HID + (long)D_HID * D_HID + N;
    long tot_threads = xthreads + prep_elems;
    k_init<<<(unsigned)((tot_threads + 255) / 256), 256, 0, stream>>>(
        x, xb, deg_i, N, (const unsigned int*)ei, npairs, flag,
        W_gcn, Wgt, W2, W2t, b_out, outacc, xthreads);

    k_deg_count<<<(E + 255) / 256, 256, 0, stream>>>(ei, flag, deg_i, E);
    k_scan1<<<NB, 256, 0, stream>>>(deg_i, bsum, N);
    k_scan23<<<NB, 256, 0, stream>>>(deg_i, bsum, NB, offs, cursor, dinv, N);
    k_fill<<<(E + 255) / 256, 256, 0, stream>>>(ei, flag, cursor, esrc, E);

    int ngroups = (N + 3) / 4;
    k_gather8<<<ngroups * 8, 256, 0, stream>>>(xb, offs, esrc, dinv, aggb, N);

    int mtiles = (N + 127) / 128;
    int gblocks = ((mtiles + 7) / 8) * 8 * 4;
    k_gemm_bf16<<<gblocks, 256, 0, stream>>>(aggb, Wgt, b_gcn, h1, N, D_IN);
    k_gemm2f<<<gblocks, 256, 0, stream>>>(h1, W2t, b2, W_out, outacc, N, D_HID);

    k_out<<<(N + 255) / 256, 256, 0, stream>>>(outacc, out, N);
}

// Round 11
// 358.877 us; speedup vs baseline: 1.2957x; 1.2957x over previous
//
#include <hip/hip_runtime.h>

#define D_IN  256
#define D_HID 512
#define NEG_SLOPE 0.2f
#define SCAN_CHUNK 2048

typedef __attribute__((ext_vector_type(8))) short short8;
typedef __attribute__((ext_vector_type(4))) float floatx4;

__device__ __forceinline__ unsigned short f2bf(float f) {
    unsigned int u = __float_as_uint(f);
    u += 0x7fffu + ((u >> 16) & 1u);   // round-to-nearest-even
    return (unsigned short)(u >> 16);
}
__device__ __forceinline__ float bf2f(unsigned short u) {
    return __uint_as_float(((unsigned int)u) << 16);
}

__device__ __forceinline__ int eidx(const void* ei, long pos, int is64) {
    return is64 ? (int)((const long long*)ei)[pos] : ((const int*)ei)[pos];
}

// ---- init: x->bf16, zero deg, dtype detect (block 0), weight transposes, outacc init ----
__global__ __launch_bounds__(256) void k_init(const float* __restrict__ x,
                                              unsigned short* __restrict__ xb,
                                              int* __restrict__ deg, int N,
                                              const unsigned int* __restrict__ ei,
                                              int npairs, int* flag,
                                              const float* __restrict__ W_gcn,
                                              unsigned short* __restrict__ Wgt,
                                              const float* __restrict__ W2,
                                              unsigned short* __restrict__ W2t,
                                              const float* __restrict__ b_out,
                                              float* __restrict__ outacc,
                                              long xthreads) {
    long t = (long)blockIdx.x * blockDim.x + threadIdx.x;
    if (t < xthreads) {
        long i = t * 4;
        float4 v = *(const float4*)(x + i);
        ushort4 o;
        o.x = f2bf(v.x); o.y = f2bf(v.y); o.z = f2bf(v.z); o.w = f2bf(v.w);
        *(ushort4*)(xb + i) = o;
        if (t < N) deg[t] = 0;
        if (blockIdx.x == 0) {
            __shared__ int nz;
            if (threadIdx.x == 0) nz = 0;
            __syncthreads();
            for (int p = threadIdx.x; p < npairs; p += blockDim.x)
                if (ei[2 * p + 1] != 0) nz = 1;
            __syncthreads();
            if (threadIdx.x == 0) *flag = nz ? 0 : 1;   // 1 => int64
        }
        return;
    }
    long u = t - xthreads;
    if (u < (long)D_IN * D_HID) {                 // Wgt [512,256]
        int tt = (int)u;
        int n = tt / D_IN, k = tt - n * D_IN;
        Wgt[tt] = f2bf(W_gcn[(long)k * D_HID + n]);
        return;
    }
    u -= (long)D_IN * D_HID;
    if (u < (long)D_HID * D_HID) {                // W2t [512,512]
        int tt = (int)u;
        int n = tt / D_HID, k = tt - n * D_HID;
        W2t[tt] = f2bf(W2[(long)k * D_HID + n]);
        return;
    }
    u -= (long)D_HID * D_HID;
    if (u < N) outacc[u] = b_out[0];
}

// ---- degree count (int only) ----
__global__ void k_deg_count(const void* __restrict__ ei, const int* __restrict__ flag,
                            int* __restrict__ deg, int E) {
    int e = blockIdx.x * blockDim.x + threadIdx.x;
    if (e < E) atomicAdd(&deg[eidx(ei, (long)E + e, *flag)], 1);
}

// ---- scan phase 1: per-chunk sums ----
__global__ __launch_bounds__(256) void k_scan1(const int* __restrict__ deg,
                                               int* __restrict__ bsum, int N) {
    int base = blockIdx.x * SCAN_CHUNK;
    int hi = min(base + SCAN_CHUNK, N);
    int s = 0;
    for (int i = base + threadIdx.x; i < hi; i += 256) s += deg[i];
#pragma unroll
    for (int off = 32; off > 0; off >>= 1) s += __shfl_down(s, off, 64);
    __shared__ int lds[4];
    if ((threadIdx.x & 63) == 0) lds[threadIdx.x >> 6] = s;
    __syncthreads();
    if (threadIdx.x == 0) bsum[blockIdx.x] = lds[0] + lds[1] + lds[2] + lds[3];
}

// ---- scan phases 2+3 merged ----
__global__ __launch_bounds__(256) void k_scan23(const int* __restrict__ deg,
                                                const int* __restrict__ bsum, int NB,
                                                int* __restrict__ offs,
                                                int* __restrict__ cursor,
                                                float* __restrict__ dinv, int N) {
    __shared__ int lds[256];
    int t = threadIdx.x;
    int bbase = 0;
    for (int i = 0; i < NB; ++i) bbase += (i < blockIdx.x) ? bsum[i] : 0;
    if (blockIdx.x == NB - 1 && t == 0) offs[N] = bbase + bsum[NB - 1];
    int base = blockIdx.x * SCAN_CHUNK;
    int lo = base + t * 8;
    int v[8], s = 0;
#pragma unroll
    for (int j = 0; j < 8; ++j) {
        int i = lo + j;
        v[j] = (i < N) ? deg[i] : 0;
        s += v[j];
    }
    lds[t] = s;
    __syncthreads();
    for (int d = 1; d < 256; d <<= 1) {
        int add = (t >= d) ? lds[t - d] : 0;
        __syncthreads();
        lds[t] += add;
        __syncthreads();
    }
    int run = bbase + ((t > 0) ? lds[t - 1] : 0);
#pragma unroll
    for (int j = 0; j < 8; ++j) {
        int i = lo + j;
        if (i < N) {
            offs[i] = run; cursor[i] = run;
            dinv[i] = rsqrtf(1.0f + (float)v[j]);
            run += v[j];
        }
    }
}

// ---- fill CSR edge list (src per slot, dst-sorted) ----
__global__ void k_fill(const void* __restrict__ ei, const int* __restrict__ flag,
                       int* __restrict__ cursor, int* __restrict__ esrc, int E) {
    int e = blockIdx.x * blockDim.x + threadIdx.x;
    if (e >= E) return;
    int is64 = *flag;
    int s = eidx(ei, e, is64), d = eidx(ei, (long)E + e, is64);
    int pos = atomicAdd(&cursor[d], 1);
    esrc[pos] = s;
}

// ---- gather: wave=node, ushort8 loads (16 B/lane), 2 edges/load, 8-edge unroll ----
__global__ __launch_bounds__(256) void k_gather(const unsigned short* __restrict__ xb,
                                                const int* __restrict__ offs,
                                                const int* __restrict__ esrc,
                                                const float* __restrict__ dinv,
                                                unsigned short* __restrict__ aggb, int N) {
    int node = blockIdx.x * 4 + (threadIdx.x >> 6);
    int lane = threadIdx.x & 63;
    if (node >= N) return;
    int half = lane >> 5;          // which edge of a pair this lane handles
    int li   = lane & 31;          // 32 lanes x ushort8 = 256 cols
    int colofs = li * 8;
    float di = dinv[node];

    float a[8];
    {
        short8 v = *(const short8*)(xb + (long)node * D_IN + colofs);
#pragma unroll
        for (int j = 0; j < 8; ++j)
            a[j] = (half == 0) ? di * bf2f((unsigned short)v[j]) : 0.f;
    }

    int beg = offs[node], end = offs[node + 1];
    int e = beg;
    for (; e + 8 <= end; e += 8) {      // 4 x 1KB wave-loads in flight
        int s0 = esrc[e + half];
        int s1 = esrc[e + 2 + half];
        int s2 = esrc[e + 4 + half];
        int s3 = esrc[e + 6 + half];
        float w0 = dinv[s0], w1 = dinv[s1], w2 = dinv[s2], w3 = dinv[s3];
        short8 u0 = *(const short8*)(xb + (long)s0 * D_IN + colofs);
        short8 u1 = *(const short8*)(xb + (long)s1 * D_IN + colofs);
        short8 u2 = *(const short8*)(xb + (long)s2 * D_IN + colofs);
        short8 u3 = *(const short8*)(xb + (long)s3 * D_IN + colofs);
#pragma unroll
        for (int j = 0; j < 8; ++j)
            a[j] += w0 * bf2f((unsigned short)u0[j]) + w1 * bf2f((unsigned short)u1[j])
                  + w2 * bf2f((unsigned short)u2[j]) + w3 * bf2f((unsigned short)u3[j]);
    }
    for (; e < end; e += 2) {           // guarded 2-edge tail
        int j0 = e + half;
        int jj = (j0 < end) ? j0 : end - 1;
        int s = esrc[jj];
        float w = (j0 < end) ? dinv[s] : 0.f;
        short8 u = *(const short8*)(xb + (long)s * D_IN + colofs);
#pragma unroll
        for (int j = 0; j < 8; ++j)
            a[j] += w * bf2f((unsigned short)u[j]);
    }

#pragma unroll
    for (int j = 0; j < 8; ++j) a[j] += __shfl_xor(a[j], 32, 64);

    if (half == 0) {
        short8 o;
#pragma unroll
        for (int j = 0; j < 8; ++j) o[j] = (short)f2bf(a[j] * di);
        *(short8*)(aggb + (long)node * D_IN + colofs) = o;
    }
}

// ============ swizzled-LDS 128x128 GEMM machinery (round-9, unchanged) ============
__device__ __forceinline__ void async_cp16(const unsigned short* gp, unsigned short* lp) {
    __builtin_amdgcn_global_load_lds((const __attribute__((address_space(1))) void*)gp,
                                     (__attribute__((address_space(3))) void*)lp, 16, 0, 0);
}

__device__ __forceinline__ void stage_sw(const unsigned short* src, int strideK,
                                         int rowMax, unsigned short* lds, int tid) {
#pragma unroll
    for (int rr = 0; rr < 2; ++rr) {
        int c = rr * 256 + tid;
        int p = c >> 3;
        int ci = (c & 7) ^ (p & 7);
        int row = 2 * p + (ci >> 2);
        if (row > rowMax) row = rowMax;
        async_cp16(src + (long)row * strideK + (ci & 3) * 8, lds + c * 8);
    }
}

__device__ __forceinline__ bool map_block(int b, int M, int& m0, int& n0) {
    int x = b & 7, slot = b >> 3;
    int mt = x + 8 * (slot >> 2);
    m0 = mt * 128; n0 = (slot & 3) * 128;
    return m0 < M;
}

// ---- GEMM1: C[M,512] = bf16(leaky(A[M,K] @ Bt[512,K]^T + bias)) ----
__global__ __launch_bounds__(256) void k_gemm_bf16(const unsigned short* __restrict__ A,
                                                   const unsigned short* __restrict__ Bt,
                                                   const float* __restrict__ bias,
                                                   unsigned short* __restrict__ C,
                                                   int M, int K) {
    __shared__ __align__(16) unsigned short As[128 * 32];
    __shared__ __align__(16) unsigned short Bs[128 * 32];
    const int tid  = threadIdx.x;
    const int lane = tid & 63, wave = tid >> 6;
    int m0, n0;
    if (!map_block(blockIdx.x, M, m0, n0)) return;
    const int r = lane & 15, q = lane >> 4;
    const int rh = r >> 1;
    const int sa = (((r & 1) << 2) | q) ^ rh;
    const int wm = (wave & 1) * 64, wn = (wave >> 1) * 64;

    floatx4 acc[4][4];
#pragma unroll
    for (int i = 0; i < 4; ++i)
#pragma unroll
        for (int j = 0; j < 4; ++j) acc[i][j] = (floatx4){0.f, 0.f, 0.f, 0.f};

    for (int k0 = 0; k0 < K; k0 += 32) {
        stage_sw(A + (long)m0 * K + k0, K, M - 1 - m0, As, tid);
        stage_sw(Bt + (long)n0 * K + k0, K, 127, Bs, tid);
        __syncthreads();

        short8 af[4], bf[4];
#pragma unroll
        for (int i = 0; i < 4; ++i)
            af[i] = *(const short8*)(As + (wm / 2 + i * 8 + rh) * 64 + sa * 8);
#pragma unroll
        for (int j = 0; j < 4; ++j)
            bf[j] = *(const short8*)(Bs + (wn / 2 + j * 8 + rh) * 64 + sa * 8);
#pragma unroll
        for (int i = 0; i < 4; ++i)
#pragma unroll
            for (int j = 0; j < 4; ++j)
                acc[i][j] = __builtin_amdgcn_mfma_f32_16x16x32_bf16(af[i], bf[j], acc[i][j], 0, 0, 0);
        __syncthreads();
    }

#pragma unroll
    for (int j = 0; j < 4; ++j) {
        int col = n0 + wn + j * 16 + r;
        float bv = bias[col];
#pragma unroll
        for (int i = 0; i < 4; ++i) {
#pragma unroll
            for (int t2 = 0; t2 < 4; ++t2) {
                int row = m0 + wm + i * 16 + q * 4 + t2;
                if (row < M) {
                    float v = acc[i][j][t2] + bv;
                    v = v > 0.f ? v : NEG_SLOPE * v;
                    C[(long)row * D_HID + col] = f2bf(v);
                }
            }
        }
    }
}

// ---- GEMM2 fused with head: outacc[row] += sum_col leaky(A@Bt^T + b2) * wout[col] ----
__global__ __launch_bounds__(256) void k_gemm2f(const unsigned short* __restrict__ A,
                                                const unsigned short* __restrict__ Bt,
                                                const float* __restrict__ bias,
                                                const float* __restrict__ wout,
                                                float* __restrict__ outacc,
                                                int M, int K) {
    __shared__ __align__(16) unsigned short As[128 * 32];
    __shared__ __align__(16) unsigned short Bs[128 * 32];
    const int tid  = threadIdx.x;
    const int lane = tid & 63, wave = tid >> 6;
    int m0, n0;
    if (!map_block(blockIdx.x, M, m0, n0)) return;
    const int r = lane & 15, q = lane >> 4;
    const int rh = r >> 1;
    const int sa = (((r & 1) << 2) | q) ^ rh;
    const int wm = (wave & 1) * 64, wn = (wave >> 1) * 64;

    floatx4 acc[4][4];
#pragma unroll
    for (int i = 0; i < 4; ++i)
#pragma unroll
        for (int j = 0; j < 4; ++j) acc[i][j] = (floatx4){0.f, 0.f, 0.f, 0.f};

    for (int k0 = 0; k0 < K; k0 += 32) {
        stage_sw(A + (long)m0 * K + k0, K, M - 1 - m0, As, tid);
        stage_sw(Bt + (long)n0 * K + k0, K, 127, Bs, tid);
        __syncthreads();

        short8 af[4], bf[4];
#pragma unroll
        for (int i = 0; i < 4; ++i)
            af[i] = *(const short8*)(As + (wm / 2 + i * 8 + rh) * 64 + sa * 8);
#pragma unroll
        for (int j = 0; j < 4; ++j)
            bf[j] = *(const short8*)(Bs + (wn / 2 + j * 8 + rh) * 64 + sa * 8);
#pragma unroll
        for (int i = 0; i < 4; ++i)
#pragma unroll
            for (int j = 0; j < 4; ++j)
                acc[i][j] = __builtin_amdgcn_mfma_f32_16x16x32_bf16(af[i], bf[j], acc[i][j], 0, 0, 0);
        __syncthreads();
    }

    float bv[4], wv[4];
#pragma unroll
    for (int j = 0; j < 4; ++j) {
        int col = n0 + wn + j * 16 + r;
        bv[j] = bias[col];
        wv[j] = wout[col];
    }
#pragma unroll
    for (int i = 0; i < 4; ++i) {
#pragma unroll
        for (int t2 = 0; t2 < 4; ++t2) {
            float p = 0.f;
#pragma unroll
            for (int j = 0; j < 4; ++j) {
                float v = acc[i][j][t2] + bv[j];
                v = v > 0.f ? v : NEG_SLOPE * v;
                p += v * wv[j];
            }
            p += __shfl_xor(p, 8, 64);
            p += __shfl_xor(p, 4, 64);
            p += __shfl_xor(p, 2, 64);
            p += __shfl_xor(p, 1, 64);
            if (r == 0) {
                int row = m0 + wm + i * 16 + q * 4 + t2;
                if (row < M) atomicAdd(&outacc[row], p);
            }
        }
    }
}

// ---- final: plain-store copy outacc (ws) -> d_out ----
__global__ void k_out(const float* __restrict__ outacc, float* __restrict__ out, int N) {
    int i = blockIdx.x * blockDim.x + threadIdx.x;
    if (i < N) out[i] = outacc[i];
}

extern "C" void kernel_launch(void* const* d_in, const int* in_sizes, int n_in,
                              void* d_out, int out_size, void* d_ws, size_t ws_size,
                              hipStream_t stream) {
    const float* x     = (const float*)d_in[0];
    const void*  ei    = d_in[1];
    const float* W_gcn = (const float*)d_in[2];
    const float* b_gcn = (const float*)d_in[3];
    const float* W2    = (const float*)d_in[4];
    const float* b2    = (const float*)d_in[5];
    const float* W_out = (const float*)d_in[6];
    const float* b_out = (const float*)d_in[7];
    float* out = (float*)d_out;

    const int N = in_sizes[0] / D_IN;
    const int E = in_sizes[1] / 2;
    const int NB = (N + SCAN_CHUNK - 1) / SCAN_CHUNK;

    char* w = (char*)d_ws;
    size_t off = 0;
    auto alloc = [&](size_t bytes) { char* p = w + off; off = (off + bytes + 255) & ~(size_t)255; return p; };
    int*            flag   = (int*)alloc(256);
    float*          dinv   = (float*)alloc((size_t)N * 4);
    int*            deg_i  = (int*)alloc((size_t)N * 4);
    int*            offs   = (int*)alloc((size_t)(N + 1) * 4);
    int*            cursor = (int*)alloc((size_t)N * 4);
    float*          outacc = (float*)alloc((size_t)N * 4);
    int*            bsum   = (int*)alloc((size_t)NB * 4);
    int*            esrc   = (int*)alloc((size_t)(E + 8) * 4);
    unsigned short* xb     = (unsigned short*)alloc((size_t)N * D_IN * 2);
    unsigned short* aggb   = (unsigned short*)alloc((size_t)N * D_IN * 2);
    unsigned short* h1     = (unsigned short*)alloc((size_t)N * D_HID * 2);
    unsigned short* Wgt    = (unsigned short*)alloc((size_t)D_IN * D_HID * 2);
    unsigned short* W2t    = (unsigned short*)alloc((size_t)D_HID * D_HID * 2);

    int npairs = E < 2048 ? E : 2048;
    long xthreads = ((long)N * D_IN) / 4;
    long prep_elems = (long)D_IN * D_HID + (long)D_HID * D_HID + N;
    long tot_threads = xthreads + prep_elems;
    k_init<<<(unsigned)((tot_threads + 255) / 256), 256, 0, stream>>>(
        x, xb, deg_i, N, (const unsigned int*)ei, npairs, flag,
        W_gcn, Wgt, W2, W2t, b_out, outacc, xthreads);

    k_deg_count<<<(E + 255) / 256, 256, 0, stream>>>(ei, flag, deg_i, E);
    k_scan1<<<NB, 256, 0, stream>>>(deg_i, bsum, N);
    k_scan23<<<NB, 256, 0, stream>>>(deg_i, bsum, NB, offs, cursor, dinv, N);
    k_fill<<<(E + 255) / 256, 256, 0, stream>>>(ei, flag, cursor, esrc, E);

    k_gather<<<(N + 3) / 4, 256, 0, stream>>>(xb, offs, esrc, dinv, aggb, N);

    int mtiles = (N + 127) / 128;
    int gblocks = ((mtiles + 7) / 8) * 8 * 4;
    k_gemm_bf16<<<gblocks, 256, 0, stream>>>(aggb, Wgt, b_gcn, h1, N, D_IN);
    k_gemm2f<<<gblocks, 256, 0, stream>>>(h1, W2t, b2, W_out, outacc, N, D_HID);

    k_out<<<(N + 255) / 256, 256, 0, stream>>>(outacc, out, N);
}

// Round 12
// 352.743 us; speedup vs baseline: 1.3182x; 1.0174x over previous
//
#include <hip/hip_runtime.h>

#define D_IN  256
#define D_HID 512
#define NEG_SLOPE 0.2f
#define SCAN_CHUNK 2048

typedef __attribute__((ext_vector_type(8))) short short8;
typedef __attribute__((ext_vector_type(4))) float floatx4;

__device__ __forceinline__ unsigned short f2bf(float f) {
    unsigned int u = __float_as_uint(f);
    u += 0x7fffu + ((u >> 16) & 1u);   // round-to-nearest-even
    return (unsigned short)(u >> 16);
}
__device__ __forceinline__ float bf2f(unsigned short u) {
    return __uint_as_float(((unsigned int)u) << 16);
}

__device__ __forceinline__ int eidx(const void* ei, long pos, int is64) {
    return is64 ? (int)((const long long*)ei)[pos] : ((const int*)ei)[pos];
}

// ---- init: x->bf16, zero deg, dtype detect (block 0), weight transposes, outacc init ----
__global__ __launch_bounds__(256) void k_init(const float* __restrict__ x,
                                              unsigned short* __restrict__ xb,
                                              int* __restrict__ deg, int N,
                                              const unsigned int* __restrict__ ei,
                                              int npairs, int* flag,
                                              const float* __restrict__ W_gcn,
                                              unsigned short* __restrict__ Wgt,
                                              const float* __restrict__ W2,
                                              unsigned short* __restrict__ W2t,
                                              const float* __restrict__ b_out,
                                              float* __restrict__ outacc,
                                              long xthreads) {
    long t = (long)blockIdx.x * blockDim.x + threadIdx.x;
    if (t < xthreads) {
        long i = t * 4;
        float4 v = *(const float4*)(x + i);
        ushort4 o;
        o.x = f2bf(v.x); o.y = f2bf(v.y); o.z = f2bf(v.z); o.w = f2bf(v.w);
        *(ushort4*)(xb + i) = o;
        if (t < N) deg[t] = 0;
        if (blockIdx.x == 0) {
            __shared__ int nz;
            if (threadIdx.x == 0) nz = 0;
            __syncthreads();
            for (int p = threadIdx.x; p < npairs; p += blockDim.x)
                if (ei[2 * p + 1] != 0) nz = 1;
            __syncthreads();
            if (threadIdx.x == 0) *flag = nz ? 0 : 1;   // 1 => int64
        }
        return;
    }
    long u = t - xthreads;
    if (u < (long)D_IN * D_HID) {                 // Wgt [512,256]
        int tt = (int)u;
        int n = tt / D_IN, k = tt - n * D_IN;
        Wgt[tt] = f2bf(W_gcn[(long)k * D_HID + n]);
        return;
    }
    u -= (long)D_IN * D_HID;
    if (u < (long)D_HID * D_HID) {                // W2t [512,512]
        int tt = (int)u;
        int n = tt / D_HID, k = tt - n * D_HID;
        W2t[tt] = f2bf(W2[(long)k * D_HID + n]);
        return;
    }
    u -= (long)D_HID * D_HID;
    if (u < N) outacc[u] = b_out[0];
}

// ---- degree count (int only) ----
__global__ void k_deg_count(const void* __restrict__ ei, const int* __restrict__ flag,
                            int* __restrict__ deg, int E) {
    int e = blockIdx.x * blockDim.x + threadIdx.x;
    if (e < E) atomicAdd(&deg[eidx(ei, (long)E + e, *flag)], 1);
}

// ---- scan phase 1: per-chunk sums ----
__global__ __launch_bounds__(256) void k_scan1(const int* __restrict__ deg,
                                               int* __restrict__ bsum, int N) {
    int base = blockIdx.x * SCAN_CHUNK;
    int hi = min(base + SCAN_CHUNK, N);
    int s = 0;
    for (int i = base + threadIdx.x; i < hi; i += 256) s += deg[i];
#pragma unroll
    for (int off = 32; off > 0; off >>= 1) s += __shfl_down(s, off, 64);
    __shared__ int lds[4];
    if ((threadIdx.x & 63) == 0) lds[threadIdx.x >> 6] = s;
    __syncthreads();
    if (threadIdx.x == 0) bsum[blockIdx.x] = lds[0] + lds[1] + lds[2] + lds[3];
}

// ---- scan phases 2+3 merged ----
__global__ __launch_bounds__(256) void k_scan23(const int* __restrict__ deg,
                                                const int* __restrict__ bsum, int NB,
                                                int* __restrict__ offs,
                                                int* __restrict__ cursor,
                                                float* __restrict__ dinv, int N) {
    __shared__ int lds[256];
    int t = threadIdx.x;
    int bbase = 0;
    for (int i = 0; i < NB; ++i) bbase += (i < blockIdx.x) ? bsum[i] : 0;
    if (blockIdx.x == NB - 1 && t == 0) offs[N] = bbase + bsum[NB - 1];
    int base = blockIdx.x * SCAN_CHUNK;
    int lo = base + t * 8;
    int v[8], s = 0;
#pragma unroll
    for (int j = 0; j < 8; ++j) {
        int i = lo + j;
        v[j] = (i < N) ? deg[i] : 0;
        s += v[j];
    }
    lds[t] = s;
    __syncthreads();
    for (int d = 1; d < 256; d <<= 1) {
        int add = (t >= d) ? lds[t - d] : 0;
        __syncthreads();
        lds[t] += add;
        __syncthreads();
    }
    int run = bbase + ((t > 0) ? lds[t - 1] : 0);
#pragma unroll
    for (int j = 0; j < 8; ++j) {
        int i = lo + j;
        if (i < N) {
            offs[i] = run; cursor[i] = run;
            dinv[i] = rsqrtf(1.0f + (float)v[j]);
            run += v[j];
        }
    }
}

// ---- fill CSR edge list (src per slot, dst-sorted) ----
__global__ void k_fill(const void* __restrict__ ei, const int* __restrict__ flag,
                       int* __restrict__ cursor, int* __restrict__ esrc, int E) {
    int e = blockIdx.x * blockDim.x + threadIdx.x;
    if (e >= E) return;
    int is64 = *flag;
    int s = eidx(ei, e, is64), d = eidx(ei, (long)E + e, is64);
    int pos = atomicAdd(&cursor[d], 1);
    esrc[pos] = s;
}

// ---- gather: wave=node, ushort8 loads (16 B/lane), 2 edges/load, 16-edge unroll ----
__global__ __launch_bounds__(256) void k_gather(const unsigned short* __restrict__ xb,
                                                const int* __restrict__ offs,
                                                const int* __restrict__ esrc,
                                                const float* __restrict__ dinv,
                                                unsigned short* __restrict__ aggb, int N) {
    int node = blockIdx.x * 4 + (threadIdx.x >> 6);
    int lane = threadIdx.x & 63;
    if (node >= N) return;
    int half = lane >> 5;          // which edge of a pair this lane handles
    int li   = lane & 31;          // 32 lanes x ushort8 = 256 cols
    int colofs = li * 8;
    float di = dinv[node];

    float a[8];
    {
        short8 v = *(const short8*)(xb + (long)node * D_IN + colofs);
#pragma unroll
        for (int j = 0; j < 8; ++j)
            a[j] = (half == 0) ? di * bf2f((unsigned short)v[j]) : 0.f;
    }

    int beg = offs[node], end = offs[node + 1];
    int e = beg;
    for (; e + 16 <= end; e += 16) {    // 8 x 1KB wave-loads in flight
        int s0 = esrc[e      + half], s1 = esrc[e +  2 + half];
        int s2 = esrc[e +  4 + half], s3 = esrc[e +  6 + half];
        int s4 = esrc[e +  8 + half], s5 = esrc[e + 10 + half];
        int s6 = esrc[e + 12 + half], s7 = esrc[e + 14 + half];
        float w0 = dinv[s0], w1 = dinv[s1], w2 = dinv[s2], w3 = dinv[s3];
        float w4 = dinv[s4], w5 = dinv[s5], w6 = dinv[s6], w7 = dinv[s7];
        short8 u0 = *(const short8*)(xb + (long)s0 * D_IN + colofs);
        short8 u1 = *(const short8*)(xb + (long)s1 * D_IN + colofs);
        short8 u2 = *(const short8*)(xb + (long)s2 * D_IN + colofs);
        short8 u3 = *(const short8*)(xb + (long)s3 * D_IN + colofs);
        short8 u4 = *(const short8*)(xb + (long)s4 * D_IN + colofs);
        short8 u5 = *(const short8*)(xb + (long)s5 * D_IN + colofs);
        short8 u6 = *(const short8*)(xb + (long)s6 * D_IN + colofs);
        short8 u7 = *(const short8*)(xb + (long)s7 * D_IN + colofs);
#pragma unroll
        for (int j = 0; j < 8; ++j)
            a[j] += w0 * bf2f((unsigned short)u0[j]) + w1 * bf2f((unsigned short)u1[j])
                  + w2 * bf2f((unsigned short)u2[j]) + w3 * bf2f((unsigned short)u3[j])
                  + w4 * bf2f((unsigned short)u4[j]) + w5 * bf2f((unsigned short)u5[j])
                  + w6 * bf2f((unsigned short)u6[j]) + w7 * bf2f((unsigned short)u7[j]);
    }
    for (; e < end; e += 2) {           // guarded 2-edge tail
        int j0 = e + half;
        int jj = (j0 < end) ? j0 : end - 1;
        int s = esrc[jj];
        float w = (j0 < end) ? dinv[s] : 0.f;
        short8 u = *(const short8*)(xb + (long)s * D_IN + colofs);
#pragma unroll
        for (int j = 0; j < 8; ++j)
            a[j] += w * bf2f((unsigned short)u[j]);
    }

#pragma unroll
    for (int j = 0; j < 8; ++j) a[j] += __shfl_xor(a[j], 32, 64);

    if (half == 0) {
        short8 o;
#pragma unroll
        for (int j = 0; j < 8; ++j) o[j] = (short)f2bf(a[j] * di);
        *(short8*)(aggb + (long)node * D_IN + colofs) = o;
    }
}

// ============ swizzled-LDS 128x128 GEMM machinery ============
__device__ __forceinline__ void async_cp16(const unsigned short* gp, unsigned short* lp) {
    __builtin_amdgcn_global_load_lds((const __attribute__((address_space(1))) void*)gp,
                                     (__attribute__((address_space(3))) void*)lp, 16, 0, 0);
}

__device__ __forceinline__ void stage_sw(const unsigned short* src, int strideK,
                                         int rowMax, unsigned short* lds, int tid) {
#pragma unroll
    for (int rr = 0; rr < 2; ++rr) {
        int c = rr * 256 + tid;
        int p = c >> 3;
        int ci = (c & 7) ^ (p & 7);
        int row = 2 * p + (ci >> 2);
        if (row > rowMax) row = rowMax;
        async_cp16(src + (long)row * strideK + (ci & 3) * 8, lds + c * 8);
    }
}

__device__ __forceinline__ bool map_block(int b, int M, int& m0, int& n0) {
    int x = b & 7, slot = b >> 3;
    int mt = x + 8 * (slot >> 2);
    m0 = mt * 128; n0 = (slot & 3) * 128;
    return m0 < M;
}

// ---- GEMM1: C[M,512] = bf16(leaky(A[M,K] @ Bt[512,K]^T + bias)), LDS-staged store ----
__global__ __launch_bounds__(256) void k_gemm_bf16(const unsigned short* __restrict__ A,
                                                   const unsigned short* __restrict__ Bt,
                                                   const float* __restrict__ bias,
                                                   unsigned short* __restrict__ C,
                                                   int M, int K) {
    __shared__ __align__(16) unsigned short As[128 * 32];
    __shared__ __align__(16) unsigned short Bs[128 * 32];
    __shared__ __align__(16) unsigned short Ep[32 * 128];   // epilogue staging, 8 KB
    const int tid  = threadIdx.x;
    const int lane = tid & 63, wave = tid >> 6;
    int m0, n0;
    if (!map_block(blockIdx.x, M, m0, n0)) return;
    const int r = lane & 15, q = lane >> 4;
    const int rh = r >> 1;
    const int sa = (((r & 1) << 2) | q) ^ rh;
    const int wm = (wave & 1) * 64, wn = (wave >> 1) * 64;
    const int band = wm >> 6;      // 0 or 1

    floatx4 acc[4][4];
#pragma unroll
    for (int i = 0; i < 4; ++i)
#pragma unroll
        for (int j = 0; j < 4; ++j) acc[i][j] = (floatx4){0.f, 0.f, 0.f, 0.f};

    for (int k0 = 0; k0 < K; k0 += 32) {
        stage_sw(A + (long)m0 * K + k0, K, M - 1 - m0, As, tid);
        stage_sw(Bt + (long)n0 * K + k0, K, 127, Bs, tid);
        __syncthreads();

        short8 af[4], bf[4];
#pragma unroll
        for (int i = 0; i < 4; ++i)
            af[i] = *(const short8*)(As + (wm / 2 + i * 8 + rh) * 64 + sa * 8);
#pragma unroll
        for (int j = 0; j < 4; ++j)
            bf[j] = *(const short8*)(Bs + (wn / 2 + j * 8 + rh) * 64 + sa * 8);
#pragma unroll
        for (int i = 0; i < 4; ++i)
#pragma unroll
            for (int j = 0; j < 4; ++j)
                acc[i][j] = __builtin_amdgcn_mfma_f32_16x16x32_bf16(af[i], bf[j], acc[i][j], 0, 0, 0);
        __syncthreads();
    }

    // epilogue: per i-band, stage 32 rows x 128 cols bf16 in LDS, then 16B/lane stores
    float bv[4];
#pragma unroll
    for (int j = 0; j < 4; ++j) bv[j] = bias[n0 + wn + j * 16 + r];

#pragma unroll
    for (int i = 0; i < 4; ++i) {
#pragma unroll
        for (int j = 0; j < 4; ++j) {
#pragma unroll
            for (int t2 = 0; t2 < 4; ++t2) {
                float v = acc[i][j][t2] + bv[j];
                v = v > 0.f ? v : NEG_SLOPE * v;
                Ep[(band * 16 + q * 4 + t2) * 128 + wn + j * 16 + r] = f2bf(v);
            }
        }
        __syncthreads();
#pragma unroll
        for (int rr = 0; rr < 2; ++rr) {
            int c = rr * 256 + tid;        // 512 chunks of 16B
            int lrow = c >> 4, ccol = c & 15;
            int grow = m0 + (lrow >> 4) * 64 + i * 16 + (lrow & 15);
            if (grow < M) {
                short8 v = *(const short8*)(Ep + lrow * 128 + ccol * 8);
                *(short8*)(C + (long)grow * D_HID + n0 + ccol * 8) = v;
            }
        }
        __syncthreads();
    }
}

// ---- GEMM2 fused with head: outacc[row] += sum_col leaky(A@Bt^T + b2) * wout[col] ----
__global__ __launch_bounds__(256) void k_gemm2f(const unsigned short* __restrict__ A,
                                                const unsigned short* __restrict__ Bt,
                                                const float* __restrict__ bias,
                                                const float* __restrict__ wout,
                                                float* __restrict__ outacc,
                                                int M, int K) {
    __shared__ __align__(16) unsigned short As[128 * 32];
    __shared__ __align__(16) unsigned short Bs[128 * 32];
    const int tid  = threadIdx.x;
    const int lane = tid & 63, wave = tid >> 6;
    int m0, n0;
    if (!map_block(blockIdx.x, M, m0, n0)) return;
    const int r = lane & 15, q = lane >> 4;
    const int rh = r >> 1;
    const int sa = (((r & 1) << 2) | q) ^ rh;
    const int wm = (wave & 1) * 64, wn = (wave >> 1) * 64;

    floatx4 acc[4][4];
#pragma unroll
    for (int i = 0; i < 4; ++i)
#pragma unroll
        for (int j = 0; j < 4; ++j) acc[i][j] = (floatx4){0.f, 0.f, 0.f, 0.f};

    for (int k0 = 0; k0 < K; k0 += 32) {
        stage_sw(A + (long)m0 * K + k0, K, M - 1 - m0, As, tid);
        stage_sw(Bt + (long)n0 * K + k0, K, 127, Bs, tid);
        __syncthreads();

        short8 af[4], bf[4];
#pragma unroll
        for (int i = 0; i < 4; ++i)
            af[i] = *(const short8*)(As + (wm / 2 + i * 8 + rh) * 64 + sa * 8);
#pragma unroll
        for (int j = 0; j < 4; ++j)
            bf[j] = *(const short8*)(Bs + (wn / 2 + j * 8 + rh) * 64 + sa * 8);
#pragma unroll
        for (int i = 0; i < 4; ++i)
#pragma unroll
            for (int j = 0; j < 4; ++j)
                acc[i][j] = __builtin_amdgcn_mfma_f32_16x16x32_bf16(af[i], bf[j], acc[i][j], 0, 0, 0);
        __syncthreads();
    }

    float bv[4], wv[4];
#pragma unroll
    for (int j = 0; j < 4; ++j) {
        int col = n0 + wn + j * 16 + r;
        bv[j] = bias[col];
        wv[j] = wout[col];
    }
#pragma unroll
    for (int i = 0; i < 4; ++i) {
#pragma unroll
        for (int t2 = 0; t2 < 4; ++t2) {
            float p = 0.f;
#pragma unroll
            for (int j = 0; j < 4; ++j) {
                float v = acc[i][j][t2] + bv[j];
                v = v > 0.f ? v : NEG_SLOPE * v;
                p += v * wv[j];
            }
            p += __shfl_xor(p, 8, 64);
            p += __shfl_xor(p, 4, 64);
            p += __shfl_xor(p, 2, 64);
            p += __shfl_xor(p, 1, 64);
            if (r == 0) {
                int row = m0 + wm + i * 16 + q * 4 + t2;
                if (row < M) atomicAdd(&outacc[row], p);
            }
        }
    }
}

// ---- final: plain-store copy outacc (ws) -> d_out ----
__global__ void k_out(const float* __restrict__ outacc, float* __restrict__ out, int N) {
    int i = blockIdx.x * blockDim.x + threadIdx.x;
    if (i < N) out[i] = outacc[i];
}

extern "C" void kernel_launch(void* const* d_in, const int* in_sizes, int n_in,
                              void* d_out, int out_size, void* d_ws, size_t ws_size,
                              hipStream_t stream) {
    const float* x     = (const float*)d_in[0];
    const void*  ei    = d_in[1];
    const float* W_gcn = (const float*)d_in[2];
    const float* b_gcn = (const float*)d_in[3];
    const float* W2    = (const float*)d_in[4];
    const float* b2    = (const float*)d_in[5];
    const float* W_out = (const float*)d_in[6];
    const float* b_out = (const float*)d_in[7];
    float* out = (float*)d_out;

    const int N = in_sizes[0] / D_IN;
    const int E = in_sizes[1] / 2;
    const int NB = (N + SCAN_CHUNK - 1) / SCAN_CHUNK;

    char* w = (char*)d_ws;
    size_t off = 0;
    auto alloc = [&](size_t bytes) { char* p = w + off; off = (off + bytes + 255) & ~(size_t)255; return p; };
    int*            flag   = (int*)alloc(256);
    float*          dinv   = (float*)alloc((size_t)N * 4);
    int*            deg_i  = (int*)alloc((size_t)N * 4);
    int*            offs   = (int*)alloc((size_t)(N + 1) * 4);
    int*            cursor = (int*)alloc((size_t)N * 4);
    float*          outacc = (float*)alloc((size_t)N * 4);
    int*            bsum   = (int*)alloc((size_t)NB * 4);
    int*            esrc   = (int*)alloc((size_t)(E + 16) * 4);
    unsigned short* xb     = (unsigned short*)alloc((size_t)N * D_IN * 2);
    unsigned short* aggb   = (unsigned short*)alloc((size_t)N * D_IN * 2);
    unsigned short* h1     = (unsigned short*)alloc((size_t)N * D_HID * 2);
    unsigned short* Wgt    = (unsigned short*)alloc((size_t)D_IN * D_HID * 2);
    unsigned short* W2t    = (unsigned short*)alloc((size_t)D_HID * D_HID * 2);

    int npairs = E < 2048 ? E : 2048;
    long xthreads = ((long)N * D_IN) / 4;
    long prep_elems = (long)D_IN * D_HID + (long)D_HID * D_HID + N;
    long tot_threads = xthreads + prep_elems;
    k_init<<<(unsigned)((tot_threads + 255) / 256), 256, 0, stream>>>(
        x, xb, deg_i, N, (const unsigned int*)ei, npairs, flag,
        W_gcn, Wgt, W2, W2t, b_out, outacc, xthreads);

    k_deg_count<<<(E + 255) / 256, 256, 0, stream>>>(ei, flag, deg_i, E);
    k_scan1<<<NB, 256, 0, stream>>>(deg_i, bsum, N);
    k_scan23<<<NB, 256, 0, stream>>>(deg_i, bsum, NB, offs, cursor, dinv, N);
    k_fill<<<(E + 255) / 256, 256, 0, stream>>>(ei, flag, cursor, esrc, E);

    k_gather<<<(N + 3) / 4, 256, 0, stream>>>(xb, offs, esrc, dinv, aggb, N);

    int mtiles = (N + 127) / 128;
    int gblocks = ((mtiles + 7) / 8) * 8 * 4;
    k_gemm_bf16<<<gblocks, 256, 0, stream>>>(aggb, Wgt, b_gcn, h1, N, D_IN);
    k_gemm2f<<<gblocks, 256, 0, stream>>>(h1, W2t, b2, W_out, outacc, N, D_HID);

    k_out<<<(N + 255) / 256, 256, 0, stream>>>(outacc, out, N);
}

// Round 13
// 337.063 us; speedup vs baseline: 1.3795x; 1.0465x over previous
//
#include <hip/hip_runtime.h>

#define D_IN  256
#define D_HID 512
#define NEG_SLOPE 0.2f
#define SCAN_CHUNK 2048

typedef __attribute__((ext_vector_type(8))) short short8;
typedef __attribute__((ext_vector_type(4))) float floatx4;

__device__ __forceinline__ unsigned short f2bf(float f) {
    unsigned int u = __float_as_uint(f);
    u += 0x7fffu + ((u >> 16) & 1u);   // round-to-nearest-even
    return (unsigned short)(u >> 16);
}
__device__ __forceinline__ float bf2f(unsigned short u) {
    return __uint_as_float(((unsigned int)u) << 16);
}

__device__ __forceinline__ int eidx(const void* ei, long pos, int is64) {
    return is64 ? (int)((const long long*)ei)[pos] : ((const int*)ei)[pos];
}

// ---- init: x->bf16, zero deg, dtype detect (block 0), weight transposes, outacc init ----
__global__ __launch_bounds__(256) void k_init(const float* __restrict__ x,
                                              unsigned short* __restrict__ xb,
                                              int* __restrict__ deg, int N,
                                              const unsigned int* __restrict__ ei,
                                              int npairs, int* flag,
                                              const float* __restrict__ W_gcn,
                                              unsigned short* __restrict__ Wgt,
                                              const float* __restrict__ W2,
                                              unsigned short* __restrict__ W2t,
                                              const float* __restrict__ b_out,
                                              float* __restrict__ outacc,
                                              long xthreads) {
    long t = (long)blockIdx.x * blockDim.x + threadIdx.x;
    if (t < xthreads) {
        long i = t * 4;
        float4 v = *(const float4*)(x + i);
        ushort4 o;
        o.x = f2bf(v.x); o.y = f2bf(v.y); o.z = f2bf(v.z); o.w = f2bf(v.w);
        *(ushort4*)(xb + i) = o;
        if (t < N) deg[t] = 0;
        if (blockIdx.x == 0) {
            __shared__ int nz;
            if (threadIdx.x == 0) nz = 0;
            __syncthreads();
            for (int p = threadIdx.x; p < npairs; p += blockDim.x)
                if (ei[2 * p + 1] != 0) nz = 1;
            __syncthreads();
            if (threadIdx.x == 0) *flag = nz ? 0 : 1;   // 1 => int64
        }
        return;
    }
    long u = t - xthreads;
    if (u < (long)D_IN * D_HID) {                 // Wgt [512,256]
        int tt = (int)u;
        int n = tt / D_IN, k = tt - n * D_IN;
        Wgt[tt] = f2bf(W_gcn[(long)k * D_HID + n]);
        return;
    }
    u -= (long)D_IN * D_HID;
    if (u < (long)D_HID * D_HID) {                // W2t [512,512]
        int tt = (int)u;
        int n = tt / D_HID, k = tt - n * D_HID;
        W2t[tt] = f2bf(W2[(long)k * D_HID + n]);
        return;
    }
    u -= (long)D_HID * D_HID;
    if (u < N) outacc[u] = b_out[0];
}

// ---- degree count (int only) ----
__global__ void k_deg_count(const void* __restrict__ ei, const int* __restrict__ flag,
                            int* __restrict__ deg, int E) {
    int e = blockIdx.x * blockDim.x + threadIdx.x;
    if (e < E) atomicAdd(&deg[eidx(ei, (long)E + e, *flag)], 1);
}

// ---- scan phase 1: per-chunk sums ----
__global__ __launch_bounds__(256) void k_scan1(const int* __restrict__ deg,
                                               int* __restrict__ bsum, int N) {
    int base = blockIdx.x * SCAN_CHUNK;
    int hi = min(base + SCAN_CHUNK, N);
    int s = 0;
    for (int i = base + threadIdx.x; i < hi; i += 256) s += deg[i];
#pragma unroll
    for (int off = 32; off > 0; off >>= 1) s += __shfl_down(s, off, 64);
    __shared__ int lds[4];
    if ((threadIdx.x & 63) == 0) lds[threadIdx.x >> 6] = s;
    __syncthreads();
    if (threadIdx.x == 0) bsum[blockIdx.x] = lds[0] + lds[1] + lds[2] + lds[3];
}

// ---- scan phases 2+3 merged ----
__global__ __launch_bounds__(256) void k_scan23(const int* __restrict__ deg,
                                                const int* __restrict__ bsum, int NB,
                                                int* __restrict__ offs,
                                                int* __restrict__ cursor,
                                                float* __restrict__ dinv, int N) {
    __shared__ int lds[256];
    int t = threadIdx.x;
    int bbase = 0;
    for (int i = 0; i < NB; ++i) bbase += (i < blockIdx.x) ? bsum[i] : 0;
    if (blockIdx.x == NB - 1 && t == 0) offs[N] = bbase + bsum[NB - 1];
    int base = blockIdx.x * SCAN_CHUNK;
    int lo = base + t * 8;
    int v[8], s = 0;
#pragma unroll
    for (int j = 0; j < 8; ++j) {
        int i = lo + j;
        v[j] = (i < N) ? deg[i] : 0;
        s += v[j];
    }
    lds[t] = s;
    __syncthreads();
    for (int d = 1; d < 256; d <<= 1) {
        int add = (t >= d) ? lds[t - d] : 0;
        __syncthreads();
        lds[t] += add;
        __syncthreads();
    }
    int run = bbase + ((t > 0) ? lds[t - 1] : 0);
#pragma unroll
    for (int j = 0; j < 8; ++j) {
        int i = lo + j;
        if (i < N) {
            offs[i] = run; cursor[i] = run;
            dinv[i] = rsqrtf(1.0f + (float)v[j]);
            run += v[j];
        }
    }
}

// ---- fill CSR edge list (src per slot, dst-sorted) ----
__global__ void k_fill(const void* __restrict__ ei, const int* __restrict__ flag,
                       int* __restrict__ cursor, int* __restrict__ esrc, int E) {
    int e = blockIdx.x * blockDim.x + threadIdx.x;
    if (e >= E) return;
    int is64 = *flag;
    int s = eidx(ei, e, is64), d = eidx(ei, (long)E + e, is64);
    int pos = atomicAdd(&cursor[d], 1);
    esrc[pos] = s;
}

// ---- gather: wave=node, ushort8 loads (16 B/lane), 2 edges/load, 8-edge unroll (r11 tuned) ----
__global__ __launch_bounds__(256) void k_gather(const unsigned short* __restrict__ xb,
                                                const int* __restrict__ offs,
                                                const int* __restrict__ esrc,
                                                const float* __restrict__ dinv,
                                                unsigned short* __restrict__ aggb, int N) {
    int node = blockIdx.x * 4 + (threadIdx.x >> 6);
    int lane = threadIdx.x & 63;
    if (node >= N) return;
    int half = lane >> 5;          // which edge of a pair this lane handles
    int li   = lane & 31;          // 32 lanes x ushort8 = 256 cols
    int colofs = li * 8;
    float di = dinv[node];

    float a[8];
    {
        short8 v = *(const short8*)(xb + (long)node * D_IN + colofs);
#pragma unroll
        for (int j = 0; j < 8; ++j)
            a[j] = (half == 0) ? di * bf2f((unsigned short)v[j]) : 0.f;
    }

    int beg = offs[node], end = offs[node + 1];
    int e = beg;
    for (; e + 8 <= end; e += 8) {      // 4 x 1KB wave-loads in flight
        int s0 = esrc[e + half];
        int s1 = esrc[e + 2 + half];
        int s2 = esrc[e + 4 + half];
        int s3 = esrc[e + 6 + half];
        float w0 = dinv[s0], w1 = dinv[s1], w2 = dinv[s2], w3 = dinv[s3];
        short8 u0 = *(const short8*)(xb + (long)s0 * D_IN + colofs);
        short8 u1 = *(const short8*)(xb + (long)s1 * D_IN + colofs);
        short8 u2 = *(const short8*)(xb + (long)s2 * D_IN + colofs);
        short8 u3 = *(const short8*)(xb + (long)s3 * D_IN + colofs);
#pragma unroll
        for (int j = 0; j < 8; ++j)
            a[j] += w0 * bf2f((unsigned short)u0[j]) + w1 * bf2f((unsigned short)u1[j])
                  + w2 * bf2f((unsigned short)u2[j]) + w3 * bf2f((unsigned short)u3[j]);
    }
    for (; e < end; e += 2) {           // guarded 2-edge tail
        int j0 = e + half;
        int jj = (j0 < end) ? j0 : end - 1;
        int s = esrc[jj];
        float w = (j0 < end) ? dinv[s] : 0.f;
        short8 u = *(const short8*)(xb + (long)s * D_IN + colofs);
#pragma unroll
        for (int j = 0; j < 8; ++j)
            a[j] += w * bf2f((unsigned short)u[j]);
    }

#pragma unroll
    for (int j = 0; j < 8; ++j) a[j] += __shfl_xor(a[j], 32, 64);

    if (half == 0) {
        short8 o;
#pragma unroll
        for (int j = 0; j < 8; ++j) o[j] = (short)f2bf(a[j] * di);
        *(short8*)(aggb + (long)node * D_IN + colofs) = o;
    }
}

// ============ swizzled-LDS 128x128 GEMM machinery ============
__device__ __forceinline__ void async_cp16(const unsigned short* gp, unsigned short* lp) {
    __builtin_amdgcn_global_load_lds((const __attribute__((address_space(1))) void*)gp,
                                     (__attribute__((address_space(3))) void*)lp, 16, 0, 0);
}

__device__ __forceinline__ void stage_sw(const unsigned short* src, int strideK,
                                         int rowMax, unsigned short* lds, int tid) {
#pragma unroll
    for (int rr = 0; rr < 2; ++rr) {
        int c = rr * 256 + tid;
        int p = c >> 3;
        int ci = (c & 7) ^ (p & 7);
        int row = 2 * p + (ci >> 2);
        if (row > rowMax) row = rowMax;
        async_cp16(src + (long)row * strideK + (ci & 3) * 8, lds + c * 8);
    }
}

__device__ __forceinline__ bool map_block(int b, int M, int& m0, int& n0) {
    int x = b & 7, slot = b >> 3;
    int mt = x + 8 * (slot >> 2);
    m0 = mt * 128; n0 = (slot & 3) * 128;
    return m0 < M;
}

// ---- GEMM1: C[M,512] = bf16(leaky(A[M,K] @ Bt[512,K]^T + bias)), LDS-staged store ----
__global__ __launch_bounds__(256) void k_gemm_bf16(const unsigned short* __restrict__ A,
                                                   const unsigned short* __restrict__ Bt,
                                                   const float* __restrict__ bias,
                                                   unsigned short* __restrict__ C,
                                                   int M, int K) {
    __shared__ __align__(16) unsigned short As[128 * 32];
    __shared__ __align__(16) unsigned short Bs[128 * 32];
    __shared__ __align__(16) unsigned short Ep[32 * 128];   // epilogue staging, 8 KB
    const int tid  = threadIdx.x;
    const int lane = tid & 63, wave = tid >> 6;
    int m0, n0;
    if (!map_block(blockIdx.x, M, m0, n0)) return;
    const int r = lane & 15, q = lane >> 4;
    const int rh = r >> 1;
    const int sa = (((r & 1) << 2) | q) ^ rh;
    const int wm = (wave & 1) * 64, wn = (wave >> 1) * 64;
    const int band = wm >> 6;      // 0 or 1

    floatx4 acc[4][4];
#pragma unroll
    for (int i = 0; i < 4; ++i)
#pragma unroll
        for (int j = 0; j < 4; ++j) acc[i][j] = (floatx4){0.f, 0.f, 0.f, 0.f};

    for (int k0 = 0; k0 < K; k0 += 32) {
        stage_sw(A + (long)m0 * K + k0, K, M - 1 - m0, As, tid);
        stage_sw(Bt + (long)n0 * K + k0, K, 127, Bs, tid);
        __syncthreads();

        short8 af[4], bf[4];
#pragma unroll
        for (int i = 0; i < 4; ++i)
            af[i] = *(const short8*)(As + (wm / 2 + i * 8 + rh) * 64 + sa * 8);
#pragma unroll
        for (int j = 0; j < 4; ++j)
            bf[j] = *(const short8*)(Bs + (wn / 2 + j * 8 + rh) * 64 + sa * 8);
#pragma unroll
        for (int i = 0; i < 4; ++i)
#pragma unroll
            for (int j = 0; j < 4; ++j)
                acc[i][j] = __builtin_amdgcn_mfma_f32_16x16x32_bf16(af[i], bf[j], acc[i][j], 0, 0, 0);
        __syncthreads();
    }

    // epilogue: per i-band, stage 32 rows x 128 cols bf16 in LDS, then 16B/lane stores
    float bv[4];
#pragma unroll
    for (int j = 0; j < 4; ++j) bv[j] = bias[n0 + wn + j * 16 + r];

#pragma unroll
    for (int i = 0; i < 4; ++i) {
#pragma unroll
        for (int j = 0; j < 4; ++j) {
#pragma unroll
            for (int t2 = 0; t2 < 4; ++t2) {
                float v = acc[i][j][t2] + bv[j];
                v = v > 0.f ? v : NEG_SLOPE * v;
                Ep[(band * 16 + q * 4 + t2) * 128 + wn + j * 16 + r] = f2bf(v);
            }
        }
        __syncthreads();
#pragma unroll
        for (int rr = 0; rr < 2; ++rr) {
            int c = rr * 256 + tid;        // 512 chunks of 16B
            int lrow = c >> 4, ccol = c & 15;
            int grow = m0 + (lrow >> 4) * 64 + i * 16 + (lrow & 15);
            if (grow < M) {
                short8 v = *(const short8*)(Ep + lrow * 128 + ccol * 8);
                *(short8*)(C + (long)grow * D_HID + n0 + ccol * 8) = v;
            }
        }
        __syncthreads();
    }
}

// ---- GEMM2 fused with head: outacc[row] += sum_col leaky(A@Bt^T + b2) * wout[col] ----
__global__ __launch_bounds__(256) void k_gemm2f(const unsigned short* __restrict__ A,
                                                const unsigned short* __restrict__ Bt,
                                                const float* __restrict__ bias,
                                                const float* __restrict__ wout,
                                                float* __restrict__ outacc,
                                                int M, int K) {
    __shared__ __align__(16) unsigned short As[128 * 32];
    __shared__ __align__(16) unsigned short Bs[128 * 32];
    const int tid  = threadIdx.x;
    const int lane = tid & 63, wave = tid >> 6;
    int m0, n0;
    if (!map_block(blockIdx.x, M, m0, n0)) return;
    const int r = lane & 15, q = lane >> 4;
    const int rh = r >> 1;
    const int sa = (((r & 1) << 2) | q) ^ rh;
    const int wm = (wave & 1) * 64, wn = (wave >> 1) * 64;

    floatx4 acc[4][4];
#pragma unroll
    for (int i = 0; i < 4; ++i)
#pragma unroll
        for (int j = 0; j < 4; ++j) acc[i][j] = (floatx4){0.f, 0.f, 0.f, 0.f};

    for (int k0 = 0; k0 < K; k0 += 32) {
        stage_sw(A + (long)m0 * K + k0, K, M - 1 - m0, As, tid);
        stage_sw(Bt + (long)n0 * K + k0, K, 127, Bs, tid);
        __syncthreads();

        short8 af[4], bf[4];
#pragma unroll
        for (int i = 0; i < 4; ++i)
            af[i] = *(const short8*)(As + (wm / 2 + i * 8 + rh) * 64 + sa * 8);
#pragma unroll
        for (int j = 0; j < 4; ++j)
            bf[j] = *(const short8*)(Bs + (wn / 2 + j * 8 + rh) * 64 + sa * 8);
#pragma unroll
        for (int i = 0; i < 4; ++i)
#pragma unroll
            for (int j = 0; j < 4; ++j)
                acc[i][j] = __builtin_amdgcn_mfma_f32_16x16x32_bf16(af[i], bf[j], acc[i][j], 0, 0, 0);
        __syncthreads();
    }

    float bv[4], wv[4];
#pragma unroll
    for (int j = 0; j < 4; ++j) {
        int col = n0 + wn + j * 16 + r;
        bv[j] = bias[col];
        wv[j] = wout[col];
    }
#pragma unroll
    for (int i = 0; i < 4; ++i) {
#pragma unroll
        for (int t2 = 0; t2 < 4; ++t2) {
            float p = 0.f;
#pragma unroll
            for (int j = 0; j < 4; ++j) {
                float v = acc[i][j][t2] + bv[j];
                v = v > 0.f ? v : NEG_SLOPE * v;
                p += v * wv[j];
            }
            p += __shfl_xor(p, 8, 64);
            p += __shfl_xor(p, 4, 64);
            p += __shfl_xor(p, 2, 64);
            p += __shfl_xor(p, 1, 64);
            if (r == 0) {
                int row = m0 + wm + i * 16 + q * 4 + t2;
                if (row < M) atomicAdd(&outacc[row], p);
            }
        }
    }
}

// ---- final: plain-store copy outacc (ws) -> d_out ----
__global__ void k_out(const float* __restrict__ outacc, float* __restrict__ out, int N) {
    int i = blockIdx.x * blockDim.x + threadIdx.x;
    if (i < N) out[i] = outacc[i];
}

extern "C" void kernel_launch(void* const* d_in, const int* in_sizes, int n_in,
                              void* d_out, int out_size, void* d_ws, size_t ws_size,
                              hipStream_t stream) {
    const float* x     = (const float*)d_in[0];
    const void*  ei    = d_in[1];
    const float* W_gcn = (const float*)d_in[2];
    const float* b_gcn = (const float*)d_in[3];
    const float* W2    = (const float*)d_in[4];
    const float* b2    = (const float*)d_in[5];
    const float* W_out = (const float*)d_in[6];
    const float* b_out = (const float*)d_in[7];
    float* out = (float*)d_out;

    const int N = in_sizes[0] / D_IN;
    const int E = in_sizes[1] / 2;
    const int NB = (N + SCAN_CHUNK - 1) / SCAN_CHUNK;

    char* w = (char*)d_ws;
    size_t off = 0;
    auto alloc = [&](size_t bytes) { char* p = w + off; off = (off + bytes + 255) & ~(size_t)255; return p; };
    int*            flag   = (int*)alloc(256);
    float*          dinv   = (float*)alloc((size_t)N * 4);
    int*            deg_i  = (int*)alloc((size_t)N * 4);
    int*            offs   = (int*)alloc((size_t)(N + 1) * 4);
    int*            cursor = (int*)alloc((size_t)N * 4);
    float*          outacc = (float*)alloc((size_t)N * 4);
    int*            bsum   = (int*)alloc((size_t)NB * 4);
    int*            esrc   = (int*)alloc((size_t)(E + 16) * 4);
    unsigned short* xb     = (unsigned short*)alloc((size_t)N * D_IN * 2);
    unsigned short* aggb   = (unsigned short*)alloc((size_t)N * D_IN * 2);
    unsigned short* h1     = (unsigned short*)alloc((size_t)N * D_HID * 2);
    unsigned short* Wgt    = (unsigned short*)alloc((size_t)D_IN * D_HID * 2);
    unsigned short* W2t    = (unsigned short*)alloc((size_t)D_HID * D_HID * 2);

    int npairs = E < 2048 ? E : 2048;
    long xthreads = ((long)N * D_IN) / 4;
    long prep_elems = (long)D_IN * D_HID + (long)D_HID * D_HID + N;
    long tot_threads = xthreads + prep_elems;
    k_init<<<(unsigned)((tot_threads + 255) / 256), 256, 0, stream>>>(
        x, xb, deg_i, N, (const unsigned int*)ei, npairs, flag,
        W_gcn, Wgt, W2, W2t, b_out, outacc, xthreads);

    k_deg_count<<<(E + 255) / 256, 256, 0, stream>>>(ei, flag, deg_i, E);
    k_scan1<<<NB, 256, 0, stream>>>(deg_i, bsum, N);
    k_scan23<<<NB, 256, 0, stream>>>(deg_i, bsum, NB, offs, cursor, dinv, N);
    k_fill<<<(E + 255) / 256, 256, 0, stream>>>(ei, flag, cursor, esrc, E);

    k_gather<<<(N + 3) / 4, 256, 0, stream>>>(xb, offs, esrc, dinv, aggb, N);

    int mtiles = (N + 127) / 128;
    int gblocks = ((mtiles + 7) / 8) * 8 * 4;
    k_gemm_bf16<<<gblocks, 256, 0, stream>>>(aggb, Wgt, b_gcn, h1, N, D_IN);
    k_gemm2f<<<gblocks, 256, 0, stream>>>(h1, W2t, b2, W_out, outacc, N, D_HID);

    k_out<<<(N + 255) / 256, 256, 0, stream>>>(outacc, out, N);
}